// Round 1
// baseline (523.423 us; speedup 1.0000x reference)
//
#include <hip/hip_runtime.h>

// Bond harmonic energy with scatter-add onto first atom of each bond.
// xyz: [N,3] f32, adj: [E,2] int32, blen/bpar: [E] f32, out: [N] f32.

__global__ void bond_energy_kernel(const float* __restrict__ xyz,
                                   const int2* __restrict__ adj,
                                   const float* __restrict__ blen,
                                   const float* __restrict__ bpar,
                                   float* __restrict__ out,
                                   int n_bonds) {
    int i = blockIdx.x * blockDim.x + threadIdx.x;
    if (i >= n_bonds) return;

    int2 ab = adj[i];
    const float* p0 = xyz + (size_t)ab.x * 3;
    const float* p1 = xyz + (size_t)ab.y * 3;

    float dx = p0[0] - p1[0];
    float dy = p0[1] - p1[1];
    float dz = p0[2] - p1[2];

    float e = sqrtf(dx * dx + dy * dy + dz * dz);
    float d = e - blen[i];
    float v = 0.5f * bpar[i] * d * d;

    atomicAdd(&out[ab.x], v);
}

extern "C" void kernel_launch(void* const* d_in, const int* in_sizes, int n_in,
                              void* d_out, int out_size, void* d_ws, size_t ws_size,
                              hipStream_t stream) {
    const float* xyz  = (const float*)d_in[0];
    const int2*  adj  = (const int2*)d_in[1];
    const float* blen = (const float*)d_in[2];
    const float* bpar = (const float*)d_in[3];
    float* out = (float*)d_out;

    const int n_bonds = in_sizes[1] / 2;   // [E,2] flat

    // out is poisoned with 0xAA before every timed launch — zero it.
    hipMemsetAsync(d_out, 0, (size_t)out_size * sizeof(float), stream);

    const int block = 256;
    const int grid = (n_bonds + block - 1) / block;
    bond_energy_kernel<<<grid, block, 0, stream>>>(xyz, adj, blen, bpar, out, n_bonds);
}